// Round 2
// baseline (502.072 us; speedup 1.0000x reference)
//
#include <hip/hip_runtime.h>

// Problem constants (from reference)
#define BATCH 1024
#define NL    64
#define NH    32
#define NG    20000
#define NC    64
#define GOI   1000

// logit blocking: 4 genes per block, 4 batch-quarters
#define GPB          4
#define LOGIT_BLOCKS ((GOI / GPB) * 4)        // 250 * 4 = 1000
#define RHO_NGRP     ((NG + 63) / 64)         // 313
#define RHO_YB       (BATCH / 64)             // 16
#define RHO_BLOCKS   (RHO_NGRP * RHO_YB)      // 5008

typedef __attribute__((ext_vector_type(8))) short  short8;
typedef __attribute__((ext_vector_type(4))) float  f32x4;

static __device__ __forceinline__ unsigned short f2bf(float f) {
    unsigned int u = __builtin_bit_cast(unsigned int, f);
    // round-to-nearest-even
    unsigned int r = (u + 0x7fffu + ((u >> 16) & 1u)) >> 16;
    return (unsigned short)r;
}

// ---------------------------------------------------------------------------
// Stage 1: h = relu(bn(latent @ W + b))  (fp32 math) -> bf16 [BATCH][NH] in ws
// ---------------------------------------------------------------------------
__global__ __launch_bounds__(256) void h_kernel(
    const float* __restrict__ latent,  // [BATCH][NL] fp32
    const float* __restrict__ W,       // [NL][NH]   fp32
    const float* __restrict__ bias,    // [NH]
    const float* __restrict__ gamma,   // [NH]
    const float* __restrict__ beta,    // [NH]
    const float* __restrict__ mean,    // [NH]
    const float* __restrict__ var,     // [NH]
    unsigned short* __restrict__ h)    // [BATCH][NH] bf16
{
    int tid = blockIdx.x * 256 + threadIdx.x;   // 0 .. BATCH*NH-1
    int b = tid >> 5;
    int k = tid & 31;
    float acc = 0.f;
    #pragma unroll 8
    for (int j = 0; j < NL; ++j)
        acc += latent[b * NL + j] * W[j * NH + k];
    acc += bias[k];
    float x = (acc - mean[k]) * rsqrtf(var[k] + 1e-5f) * gamma[k] + beta[k];
    x = fmaxf(x, 0.f);
    h[tid] = f2bf(x);
}

// ---------------------------------------------------------------------------
// Stage 2+3 merged. blockIdx.x < LOGIT_BLOCKS -> logit role, else rho role.
//
// logit role: 4 genes per block (fragments held in regs), 256 batches
//   (blockIdx-quarter). Per it: all 16 accs (4 genes x 4 c-tiles) computed
//   first, THEN stored b-major so each batch row gets a contiguous 1 KB
//   burst (4 genes x 256 B) -> full-line, page-local HBM writes.
//
// rho role: 64 n x 64 b per block; all 4 c-tile accs computed first, then
//   stored b-major -> 256 B contiguous burst per batch row.
// ---------------------------------------------------------------------------
__global__ __launch_bounds__(256) void main_kernel(
    const unsigned short* __restrict__ h,      // [BATCH][NH] bf16 (ws)
    const float*          __restrict__ ltab,   // [NG][NH][NC] fp32
    const int*            __restrict__ genes,  // [GOI] int32
    const float*          __restrict__ rtab,   // [NG][NH] fp32
    float*                __restrict__ out_logit, // [BATCH][GOI][NC]
    float*                __restrict__ out_rho)   // [BATCH][NG]
{
    const int wave = threadIdx.x >> 6;
    const int lane = threadIdx.x & 63;
    const int l15  = lane & 15;
    const int quad = lane >> 4;
    const int bx   = blockIdx.x;

    if (bx < LOGIT_BLOCKS) {
        // ------------------------------ logit ------------------------------
        const int gt  = bx >> 2;          // gene-tile 0..249
        const int ybl = bx & 3;           // batch quarter
        const int g0  = gt * GPB;

        // Gather 4 gene tables -> bf16 B-fragments.
        // B[k][n]: lane holds n = l15 (c within tile), k = quad*8 + j.
        short8 bf[GPB][4];
        #pragma unroll
        for (int g = 0; g < GPB; ++g) {
            const long long gene = (long long)genes[g0 + g];
            const float* lw = ltab + gene * (long long)(NH * NC);
            #pragma unroll
            for (int t = 0; t < 4; ++t) {
                #pragma unroll
                for (int j = 0; j < 8; ++j)
                    bf[g][t][j] = (short)f2bf(lw[(quad * 8 + j) * NC + t * 16 + l15]);
            }
        }

        #pragma unroll
        for (int it = 0; it < 4; ++it) {
            const int b0 = ybl * 256 + it * 64 + wave * 16;
            // A fragment: A[m][k], m = l15 (batch row), k = quad*8 + j
            short8 af = *(const short8*)(h + (b0 + l15) * NH + quad * 8);

            f32x4 acc[GPB][4];
            #pragma unroll
            for (int g = 0; g < GPB; ++g) {
                #pragma unroll
                for (int t = 0; t < 4; ++t) {
                    f32x4 z = {0.f, 0.f, 0.f, 0.f};
                    acc[g][t] = __builtin_amdgcn_mfma_f32_16x16x32_bf16(af, bf[g][t], z, 0, 0, 0);
                }
            }

            // Store b-major: for each owned batch row, write 4 genes x 4
            // c-tiles back-to-back -> 1 KB contiguous burst per row.
            // C/D layout: col = l15 (c), row = quad*4 + r (b).
            #pragma unroll
            for (int r = 0; r < 4; ++r) {
                const long long b = b0 + quad * 4 + r;
                float* op = out_logit + (b * GOI + g0) * NC + l15;
                #pragma unroll
                for (int g = 0; g < GPB; ++g) {
                    #pragma unroll
                    for (int t = 0; t < 4; ++t)
                        op[g * NC + t * 16] = acc[g][t][r];
                }
            }
        }
    } else {
        // ------------------------------- rho -------------------------------
        const int rb = bx - LOGIT_BLOCKS;
        const int yb = rb & 15;           // batch 64-group
        const int ng = rb >> 4;           // n-group of 64
        const int b0 = yb * 64 + wave * 16;

        short8 af = *(const short8*)(h + (b0 + l15) * NH + quad * 8);

        f32x4 acc[4];
        #pragma unroll
        for (int t = 0; t < 4; ++t) {
            const int n0 = ng * 64 + t * 16;
            if (n0 < NG) {
                // B[k][n] = rtab[n][k]: lane n = n0+l15, k = quad*8+j
                // (32 B contiguous per lane -> 2x dwordx4)
                const float* rp = rtab + (long long)(n0 + l15) * NH + quad * 8;
                short8 bfr;
                #pragma unroll
                for (int j = 0; j < 8; ++j)
                    bfr[j] = (short)f2bf(rp[j]);
                f32x4 z = {0.f, 0.f, 0.f, 0.f};
                acc[t] = __builtin_amdgcn_mfma_f32_16x16x32_bf16(af, bfr, z, 0, 0, 0);
            }
        }

        // Store b-major: per owned batch row, up to 4 x 64 B = 256 B burst.
        #pragma unroll
        for (int r = 0; r < 4; ++r) {
            const long long b = b0 + quad * 4 + r;
            float* op = out_rho + b * NG + ng * 64 + l15;
            #pragma unroll
            for (int t = 0; t < 4; ++t) {
                if (ng * 64 + t * 16 < NG)
                    op[t * 16] = acc[t][r];
            }
        }
    }
}

extern "C" void kernel_launch(void* const* d_in, const int* in_sizes, int n_in,
                              void* d_out, int out_size, void* d_ws, size_t ws_size,
                              hipStream_t stream) {
    const float* latent = (const float*)d_in[0];
    const int*   genes  = (const int*)d_in[1];
    const float* W      = (const float*)d_in[2];
    const float* bias   = (const float*)d_in[3];
    const float* gamma  = (const float*)d_in[4];
    const float* beta   = (const float*)d_in[5];
    const float* mean   = (const float*)d_in[6];
    const float* var    = (const float*)d_in[7];
    const float* ltab   = (const float*)d_in[8];
    const float* rtab   = (const float*)d_in[9];

    float* out = (float*)d_out;
    unsigned short* h = (unsigned short*)d_ws;   // 1024*32*2 = 64 KB

    float* out_logit = out;
    float* out_rho   = out + (long long)BATCH * GOI * NC;

    h_kernel<<<dim3((BATCH * NH) / 256), 256, 0, stream>>>(
        latent, W, bias, gamma, beta, mean, var, h);

    // logit blocks first (heavier), rho blocks fill the tail.
    main_kernel<<<dim3(LOGIT_BLOCKS + RHO_BLOCKS), 256, 0, stream>>>(
        h, ltab, genes, rtab, out_logit, out_rho);
}

// Round 6
// 476.667 us; speedup vs baseline: 1.0533x; 1.0533x over previous
//
#include <hip/hip_runtime.h>

// Problem constants (from reference)
#define BATCH 1024
#define NL    64
#define NH    32
#define NG    20000
#define NC    64
#define GOI   1000

// logit role: 1 gene per block, 4 batch-quarters
#define LOGIT_BLOCKS (GOI * 4)                // 4000
#define RHO_NGRP     ((NG + 63) / 64)         // 313
#define RHO_YB       (BATCH / 64)             // 16
#define RHO_BLOCKS   (RHO_NGRP * RHO_YB)      // 5008

typedef __attribute__((ext_vector_type(8))) short  short8;
typedef __attribute__((ext_vector_type(4))) float  f32x4;

static __device__ __forceinline__ unsigned short f2bf(float f) {
    unsigned int u = __builtin_bit_cast(unsigned int, f);
    // round-to-nearest-even
    unsigned int r = (u + 0x7fffu + ((u >> 16) & 1u)) >> 16;
    return (unsigned short)r;
}

// ---------------------------------------------------------------------------
// Stage 1: h = relu(bn(latent @ W + b))  (fp32 math) -> bf16 [BATCH][NH] in ws
// ---------------------------------------------------------------------------
__global__ __launch_bounds__(256) void h_kernel(
    const float* __restrict__ latent,  // [BATCH][NL] fp32
    const float* __restrict__ W,       // [NL][NH]   fp32
    const float* __restrict__ bias,    // [NH]
    const float* __restrict__ gamma,   // [NH]
    const float* __restrict__ beta,    // [NH]
    const float* __restrict__ mean,    // [NH]
    const float* __restrict__ var,     // [NH]
    unsigned short* __restrict__ h)    // [BATCH][NH] bf16
{
    int tid = blockIdx.x * 256 + threadIdx.x;   // 0 .. BATCH*NH-1
    int b = tid >> 5;
    int k = tid & 31;
    float acc = 0.f;
    #pragma unroll 8
    for (int j = 0; j < NL; ++j)
        acc += latent[b * NL + j] * W[j * NH + k];
    acc += bias[k];
    float x = (acc - mean[k]) * rsqrtf(var[k] + 1e-5f) * gamma[k] + beta[k];
    x = fmaxf(x, 0.f);
    h[tid] = f2bf(x);
}

// ---------------------------------------------------------------------------
// Stage 2+3 merged; TRANSPOSED MFMA (swap A/B operands) so the C/D layout
// puts 4 CONSECUTIVE output columns in each lane's acc[0..3]:
//   mfma(lw_frag, h_frag): D[c'][b'], col(l15)=batch row, row(quad*4+r)=c.
// -> one global_store_dwordx4 (16 B/lane) per c-tile: 4 store insts per
//    16x64 tile instead of 16, no LDS, no barriers, no repack.
// Fragment gathers are bit-identical to the untransposed version (A-slot
// read pattern for lw == old B-slot pattern; B-slot pattern for h == old
// A-slot pattern), so numerics are unchanged.
// ---------------------------------------------------------------------------
__global__ __launch_bounds__(256) void main_kernel(
    const unsigned short* __restrict__ h,      // [BATCH][NH] bf16 (ws)
    const float*          __restrict__ ltab,   // [NG][NH][NC] fp32
    const int*            __restrict__ genes,  // [GOI] int32
    const float*          __restrict__ rtab,   // [NG][NH] fp32
    float*                __restrict__ out_logit, // [BATCH][GOI][NC]
    float*                __restrict__ out_rho)   // [BATCH][NG]
{
    const int wave = threadIdx.x >> 6;
    const int lane = threadIdx.x & 63;
    const int l15  = lane & 15;
    const int quad = lane >> 4;
    const int bx   = blockIdx.x;

    if (bx < LOGIT_BLOCKS) {
        // ------------------------------ logit ------------------------------
        const int g   = bx >> 2;          // gene 0..999
        const int ybl = bx & 3;           // batch quarter

        const long long gene = (long long)genes[g];
        const float* lw = ltab + gene * (long long)(NH * NC);

        // A-operand fragments (A[m][k], m = c within tile, k = NH):
        // lane holds m = l15, k = quad*8 + j
        short8 bf[4];
        #pragma unroll
        for (int t = 0; t < 4; ++t) {
            #pragma unroll
            for (int j = 0; j < 8; ++j)
                bf[t][j] = (short)f2bf(lw[(quad * 8 + j) * NC + t * 16 + l15]);
        }

        #pragma unroll
        for (int it = 0; it < 4; ++it) {
            const int b0 = ybl * 256 + it * 64 + wave * 16;
            // B-operand: B[k][n], n = l15 (batch row), k = quad*8 + j
            short8 af = *(const short8*)(h + (b0 + l15) * NH + quad * 8);

            f32x4 acc[4];
            #pragma unroll
            for (int t = 0; t < 4; ++t) {
                f32x4 z = {0.f, 0.f, 0.f, 0.f};
                acc[t] = __builtin_amdgcn_mfma_f32_16x16x32_bf16(bf[t], af, z, 0, 0, 0);
            }

            // D[c'][b']: col = l15 = batch, row = quad*4+r = c (consecutive!)
            // -> 16B store per tile; 4 insts complete each row's 256 B.
            float* op = out_logit +
                ((long long)(b0 + l15) * GOI + g) * NC + quad * 4;
            #pragma unroll
            for (int t = 0; t < 4; ++t)
                *(f32x4*)(op + t * 16) = acc[t];
        }
    } else {
        // ------------------------------- rho -------------------------------
        const int rb = bx - LOGIT_BLOCKS;
        const int yb = rb & 15;           // batch 64-group
        const int ng = rb >> 4;           // n-group of 64
        const int b0 = yb * 64 + wave * 16;

        // B-operand: h fragment, n = l15 (batch row)
        short8 af = *(const short8*)(h + (b0 + l15) * NH + quad * 8);

        #pragma unroll
        for (int t = 0; t < 4; ++t) {
            const int n0 = ng * 64 + t * 16;
            if (n0 < NG) {   // NG % 16 == 0, tile fully in-range when n0 < NG
                // A-operand: A[m][k], m = n' = l15, k = quad*8+j
                // (32 B contiguous per lane)
                const float* rp = rtab + (long long)(n0 + l15) * NH + quad * 8;
                short8 bfr;
                #pragma unroll
                for (int j = 0; j < 8; ++j)
                    bfr[j] = (short)f2bf(rp[j]);
                f32x4 z = {0.f, 0.f, 0.f, 0.f};
                f32x4 acc = __builtin_amdgcn_mfma_f32_16x16x32_bf16(bfr, af, z, 0, 0, 0);
                // D[n'][b']: col = l15 = batch, row = quad*4+r = n (consec.)
                float* op = out_rho +
                    (long long)(b0 + l15) * NG + n0 + quad * 4;
                *(f32x4*)op = acc;
            }
        }
    }
}

extern "C" void kernel_launch(void* const* d_in, const int* in_sizes, int n_in,
                              void* d_out, int out_size, void* d_ws, size_t ws_size,
                              hipStream_t stream) {
    const float* latent = (const float*)d_in[0];
    const int*   genes  = (const int*)d_in[1];
    const float* W      = (const float*)d_in[2];
    const float* bias   = (const float*)d_in[3];
    const float* gamma  = (const float*)d_in[4];
    const float* beta   = (const float*)d_in[5];
    const float* mean   = (const float*)d_in[6];
    const float* var    = (const float*)d_in[7];
    const float* ltab   = (const float*)d_in[8];
    const float* rtab   = (const float*)d_in[9];

    float* out = (float*)d_out;
    unsigned short* h = (unsigned short*)d_ws;   // 1024*32*2 = 64 KB

    float* out_logit = out;
    float* out_rho   = out + (long long)BATCH * GOI * NC;

    h_kernel<<<dim3((BATCH * NH) / 256), 256, 0, stream>>>(
        latent, W, bias, gamma, beta, mean, var, h);

    main_kernel<<<dim3(LOGIT_BLOCKS + RHO_BLOCKS), 256, 0, stream>>>(
        h, ltab, genes, rtab, out_logit, out_rho);
}